// Round 23
// baseline (72.227 us; speedup 1.0000x reference)
//
#include <hip/hip_runtime.h>

// TempCtxAttention — proj_all reverted to R19-measured structure (best total, 69.8us);
// fused = R22 + rolling qa prefetch (head h loads head h+1's Q frag).
// ws (u16): kfrag[8388608] | vt3[8388608] | qp[65536] | wof[65536] | wfq[65536] | wfk[65536] | wfv[65536]
// kfrag: QK A-frags [m][h][kt(8)][ln(64)][8]   ln=(d>>3)*16+(kl&15), elem d&7
// vt3 : PV A-frags  [m][h][jt(2)][kt(8)][ln(64)][4]  ln=((kl>>2)&3)*16+(d&15), elem kl&3, jt=d>>4
// qp  : row-major [n][256]
// wof : outproj K=32 A-frags [h(8)][jtile(16)][ln(64)][8]
// wf* : proj W frags [jtile(16)][kk(8)][ln(64)][8]

typedef unsigned short u16;
typedef unsigned int u32;
typedef __attribute__((ext_vector_type(8))) _Float16 half8;
typedef __attribute__((ext_vector_type(4))) _Float16 half4;
typedef __attribute__((ext_vector_type(4))) float f32x4;
typedef __attribute__((ext_vector_type(4))) unsigned short us4;
typedef __attribute__((ext_vector_type(2))) unsigned int u32x2;

__device__ __forceinline__ u16 f2h(float v) {
  _Float16 h = (_Float16)v;
  return __builtin_bit_cast(u16, h);
}
__device__ __forceinline__ u32 pk2(float lo, float hi) {
  return (u32)f2h(lo) | ((u32)f2h(hi) << 16);
}
__device__ __forceinline__ u32 pkrtz(float lo, float hi) {   // v_cvt_pkrtz_f16_f32
  return __builtin_bit_cast(u32, __builtin_amdgcn_cvt_pkrtz(lo, hi));
}
__device__ __forceinline__ f32x4 mf16(half8 a, half8 b, f32x4 c) {
  return __builtin_amdgcn_mfma_f32_16x16x32_f16(a, b, c, 0, 0, 0);
}
__device__ __forceinline__ f32x4 mf16k16(half4 a, half4 b, f32x4 c) {
  return __builtin_amdgcn_mfma_f32_16x16x16f16(a, b, c, 0, 0, 0);
}
__device__ __forceinline__ void gload_lds16(const void* g, void* l) {
  __builtin_amdgcn_global_load_lds((const __attribute__((address_space(1))) u32*)g,
                                   (__attribute__((address_space(3))) u32*)l, 16, 0, 0);
}

// ---------------- weight conversion (unchanged): f32 -> f16 pre-fragmented ----------------
__global__ __launch_bounds__(256) void wcvt_kernel(const float* __restrict__ Wq,
                                                   const float* __restrict__ Wk,
                                                   const float* __restrict__ Wv,
                                                   const float* __restrict__ Wo,
                                                   u16* __restrict__ wfq, u16* __restrict__ wfk,
                                                   u16* __restrict__ wfv, u16* __restrict__ wof) {
  int t = blockIdx.x * 256 + threadIdx.x;     // [0, 32768)
  int widx = t >> 13, tl = t & 8191;          // 8192 entries per matrix
  int ln = tl & 63, kk = (tl >> 6) & 7, jt = tl >> 9;   // jt in [0,16)
  const float* src = widx == 0 ? Wq : widx == 1 ? Wk : widx == 2 ? Wv : Wo;
  u16* dst = widx == 0 ? wfq : widx == 1 ? wfk : widx == 2 ? wfv : wof;
  int j = jt * 16 + (ln & 15);
  int k0 = kk * 32 + (ln >> 4) * 8;
  float4 g0 = *(const float4*)(src + j * 256 + k0);
  float4 g1 = *(const float4*)(src + j * 256 + k0 + 4);
  us4 h0 = { f2h(g0.x), f2h(g0.y), f2h(g0.z), f2h(g0.w) };
  us4 h1 = { f2h(g1.x), f2h(g1.y), f2h(g1.z), f2h(g1.w) };
  int idx8 = (widx == 3) ? ((kk * 16 + jt) * 64 + ln)     // wof: head(kk)-major, K=32 frags
                         : ((jt * 8 + kk) * 64 + ln);     // wf : jtile-major
  *(us4*)(dst + idx8 * 8) = h0;
  *(us4*)(dst + idx8 * 8 + 4) = h1;
}

// ---------------- merged projections (R19-measured structure, verbatim) --------------------
// grid 4112: [0,2048) K (mode1) ; [2048,4096) V (mode2) ; [4096,4112) Q (mode0)
__global__ __launch_bounds__(256, 4) void proj_all_kernel(const float* __restrict__ query,
                                                          const float* __restrict__ key,
                                                          const float* __restrict__ value,
                                                          const u16* __restrict__ wfq,
                                                          const u16* __restrict__ wfk,
                                                          const u16* __restrict__ wfv,
                                                          const float* __restrict__ bq,
                                                          const float* __restrict__ bk,
                                                          const float* __restrict__ bv,
                                                          u16* __restrict__ qp,
                                                          u16* __restrict__ kfrag,
                                                          u16* __restrict__ vt3) {
  __shared__ __align__(16) u16 xa[64 * 256];    // 32 KB f16, XOR-swizzled
  int bid = blockIdx.x;
  int mode, logical;
  const float* X; const u16* wf; const float* bias; u16* out;
  if (bid < 2048) {
    mode = 1; X = key; wf = wfk; bias = bk; out = kfrag;
    logical = (bid & 7) * 256 + (bid >> 3);
  } else if (bid < 4096) {
    int b = bid - 2048;
    mode = 2; X = value; wf = wfv; bias = bv; out = vt3;
    logical = (b & 7) * 256 + (b >> 3);
  } else {
    mode = 0; X = query; wf = wfq; bias = bq; out = qp;
    logical = bid - 4096;
  }
  int rb = logical >> 2, cb = logical & 3;
  int tid = threadIdx.x;
  char* xb = (char*)xa;
#pragma unroll
  for (int i = 0; i < 16; ++i) {
    int idx = tid + i * 256;
    int row = idx >> 6, c4 = idx & 63;
    int so = (row * 512 + c4 * 8) ^ ((row & 7) << 4);
    float4 gx = *(const float4*)(X + (rb * 64 + row) * 256 + c4 * 4);
    us4 hx = { f2h(gx.x), f2h(gx.y), f2h(gx.z), f2h(gx.w) };
    *(us4*)(xb + so) = hx;
  }
  __syncthreads();

  int lane = tid & 63, w = tid >> 6;
  int lr = lane & 15, lq = lane >> 4;

  if (mode == 2) {
    // direct: A = X rows (this wave: w*16..+16), B = W cols; D[row=kl][col=j]
    half8 a[8];
#pragma unroll
    for (int kk = 0; kk < 8; ++kk)
      a[kk] = *(const half8*)(xb + (((w * 16 + lr) * 512 + kk * 64 + lq * 16) ^ ((lr & 7) << 4)));
#pragma unroll
    for (int ct = 0; ct < 4; ++ct) {
      int jtile = cb * 4 + ct;
      f32x4 acc = {0.f, 0.f, 0.f, 0.f};
#pragma unroll
      for (int kk = 0; kk < 8; ++kk) {
        half8 b = *(const half8*)(wf + ((jtile * 8 + kk) * 64 + lane) * 8);
        acc = mf16(a[kk], b, acc);
      }
      int j = jtile * 16 + lr;
      float bj = bias[j];
      int h = j >> 5, d = j & 31;
      int gr0 = rb * 64 + w * 16 + lq * 4;     // 4 consecutive kl (elem = kl&3)
      int mm = gr0 >> 7, kl0 = gr0 & 127;
      int base = (((mm * 8 + h) * 2 + (d >> 4)) * 8 + (kl0 >> 4)) * 256
               + (((kl0 >> 2) & 3) * 16 + (d & 15)) * 4;
      us4 st = { f2h(acc[0] + bj), f2h(acc[1] + bj), f2h(acc[2] + bj), f2h(acc[3] + bj) };
      *(us4*)(out + base) = st;
    }
  } else {
    // transposed: A = W (wave jtile = cb*4+w), B = X; D[row=j][col=gr]
    int jtile = cb * 4 + w;
    half8 a[8];
#pragma unroll
    for (int kk = 0; kk < 8; ++kk)
      a[kk] = *(const half8*)(wf + ((jtile * 8 + kk) * 64 + lane) * 8);
    int j0 = jtile * 16 + lq * 4;              // 4 consecutive j (= d)
    float4 bv4 = *(const float4*)(bias + j0);
    int h = j0 >> 5, d0 = j0 & 31;
#pragma unroll
    for (int ct = 0; ct < 4; ++ct) {
      f32x4 acc = {0.f, 0.f, 0.f, 0.f};
#pragma unroll
      for (int kk = 0; kk < 8; ++kk) {
        half8 b = *(const half8*)(xb + (((ct * 16 + lr) * 512 + kk * 64 + lq * 16) ^ ((lr & 7) << 4)));
        acc = mf16(a[kk], b, acc);
      }
      int gr = rb * 64 + ct * 16 + lr;
      us4 st = { f2h(acc[0] + bv4.x), f2h(acc[1] + bv4.y), f2h(acc[2] + bv4.z), f2h(acc[3] + bv4.w) };
      if (mode == 0) {
        *(us4*)(out + gr * 256 + j0) = st;     // qp row-major [n][256]
      } else {
        int mm = gr >> 7, kl = gr & 127;
        int idx = (mm * 8 + h) * 4096 + (kl >> 4) * 512
                + ((d0 >> 3) * 16 + (kl & 15)) * 8 + (d0 & 7);
        *(us4*)(out + idx) = st;
      }
    }
  }
}

// ---------------- fused attention + output projection (R22 + rolling qa prefetch) ----------
__global__ __launch_bounds__(512, 4) void fused_attn_kernel(const u16* __restrict__ qp,
                                                            const u16* __restrict__ kp,
                                                            const u16* __restrict__ vt3,
                                                            const u16* __restrict__ wof,
                                                            const float* __restrict__ bo,
                                                            float* __restrict__ out) {
  __shared__ __align__(16) u16 kbuf[2][4096];   // per-head QK A-frags, dbuf
  __shared__ __align__(16) u16 vbuf[2][4096];   // per-head PV A-frags, dbuf
  __shared__ __align__(16) u16 cbuf[2][4096];   // per-head ctx B-frags [nb][lane][8], dbuf

  const int bid = blockIdx.x;
  const int xcd = bid & 7, idx = bid >> 3;
  const int m = xcd * 32 + (idx >> 1);
  const int nh = idx & 1;
  const int tid = threadIdx.x;
  const int w = tid >> 6, lane = tid & 63;
  const int lr = lane & 15, lq = lane >> 4;
  const int n0 = nh * 128 + w * 16;
  const float SCL2E = 0.25506980508f;           // log2(e)/sqrt(32)

  const char* kg = (const char*)(kp + m * 8 * 4096);   // 8KB per head
  const char* vg = (const char*)(vt3 + m * 8 * 4096);

  gload_lds16(kg + w * 1024 + lane * 16, (char*)(&kbuf[0][0]) + w * 1024);
  gload_lds16(vg + w * 1024 + lane * 16, (char*)(&vbuf[0][0]) + w * 1024);
  // rolling qa prefetch: head 0's Q frag issued in the prologue
  half8 qa_next = *(const half8*)(qp + (n0 + lr) * 256 + 0 * 32 + lq * 8);
  __syncthreads();

  f32x4 accO[2][8];
#pragma unroll
  for (int jt = 0; jt < 2; ++jt)
#pragma unroll
    for (int nb = 0; nb < 8; ++nb) accO[jt][nb] = f32x4{0.f, 0.f, 0.f, 0.f};

  for (int h = 0; h < 8; ++h) {
    const int cur = h & 1;
    char* kb = (char*)(&kbuf[cur][0]);
    char* vb = (char*)(&vbuf[cur][0]);
    char* cb = (char*)(&cbuf[cur][0]);
    if (h < 7) {   // stage next head; drained by this head's __syncthreads
      gload_lds16(kg + (h + 1) * 8192 + w * 1024 + lane * 16, (char*)(&kbuf[cur ^ 1][0]) + w * 1024);
      gload_lds16(vg + (h + 1) * 8192 + w * 1024 + lane * 16, (char*)(&vbuf[cur ^ 1][0]) + w * 1024);
    }
    half8 qa = qa_next;
    if (h < 7)     // prefetch next head's Q frag (consumed next iteration)
      qa_next = *(const half8*)(qp + (n0 + lr) * 256 + (h + 1) * 32 + lq * 8);
    // ---- scores^T ----
    f32x4 s[8];
    __builtin_amdgcn_s_setprio(1);
#pragma unroll
    for (int kt = 0; kt < 8; ++kt) {
      half8 ka = *(const half8*)(kb + kt * 1024 + lane * 16);
      f32x4 z = {0.f, 0.f, 0.f, 0.f};
      s[kt] = mf16(ka, qa, z);
    }
    __builtin_amdgcn_s_setprio(0);
    // ---- max-free softmax: exp2 direct, pkrtz pack, 2 shfl for sum ----
    float sA = 0.f, sB = 0.f;
    half4 pb[8];
#pragma unroll
    for (int kt = 0; kt < 8; ++kt) {
      float p0 = __builtin_amdgcn_exp2f(s[kt][0] * SCL2E);
      float p1 = __builtin_amdgcn_exp2f(s[kt][1] * SCL2E);
      float p2 = __builtin_amdgcn_exp2f(s[kt][2] * SCL2E);
      float p3 = __builtin_amdgcn_exp2f(s[kt][3] * SCL2E);
      sA += p0 + p1; sB += p2 + p3;
      u32x2 pw = { pkrtz(p0, p1), pkrtz(p2, p3) };
      pb[kt] = __builtin_bit_cast(half4, pw);
    }
    float sum = sA + sB;
    sum += __shfl_xor(sum, 16);
    sum += __shfl_xor(sum, 32);
    float inv = 1.0f / sum;
    // ---- PV ----
    f32x4 a0 = {0.f, 0.f, 0.f, 0.f}, a1 = {0.f, 0.f, 0.f, 0.f};
    __builtin_amdgcn_s_setprio(1);
#pragma unroll
    for (int kt = 0; kt < 8; ++kt) {
      half4 v0 = *(const half4*)(vb + kt * 512 + lane * 8);
      a0 = mf16k16(v0, pb[kt], a0);
      half4 v1 = *(const half4*)(vb + 4096 + kt * 512 + lane * 8);
      a1 = mf16k16(v1, pb[kt], a1);
    }
    __builtin_amdgcn_s_setprio(0);
    // ---- wof loads issued here (hoisted): complete during the barrier's vmcnt drain ----
    half8 wv0 = *(const half8*)(wof + ((h * 16 + w * 2 + 0) * 64 + lane) * 8);
    half8 wv1 = *(const half8*)(wof + ((h * 16 + w * 2 + 1) * 64 + lane) * 8);
    // ---- ctx frags -> LDS (outproj K=32 B-frag layout) ----
    u32x2 c0 = { pk2(a0[0] * inv, a0[1] * inv), pk2(a0[2] * inv, a0[3] * inv) };
    u32x2 c1 = { pk2(a1[0] * inv, a1[1] * inv), pk2(a1[2] * inv, a1[3] * inv) };
    const int cwo = w * 1024 + ((lq >> 1) * 16 + lr) * 16 + (lq & 1) * 8;
    *(u32x2*)(cb + cwo) = c0;
    *(u32x2*)(cb + cwo + 512) = c1;
    __syncthreads();
    // ---- out-proj ----
    __builtin_amdgcn_s_setprio(1);
#pragma unroll
    for (int nb = 0; nb < 8; ++nb) {
      half8 cf = *(const half8*)(cb + nb * 1024 + lane * 16);
      accO[0][nb] = mf16(wv0, cf, accO[0][nb]);
      accO[1][nb] = mf16(wv1, cf, accO[1][nb]);
    }
    __builtin_amdgcn_s_setprio(0);
  }
#pragma unroll
  for (int jt = 0; jt < 2; ++jt) {
    const int j0 = w * 32 + jt * 16 + lq * 4;
    float4 bv = *(const float4*)(bo + j0);
#pragma unroll
    for (int nb = 0; nb < 8; ++nb) {
      const int n = nh * 128 + nb * 16 + lr;
      float4 r;
      r.x = accO[jt][nb][0] + bv.x;
      r.y = accO[jt][nb][1] + bv.y;
      r.z = accO[jt][nb][2] + bv.z;
      r.w = accO[jt][nb][3] + bv.w;
      *(float4*)(out + (n * 256 + m) * 256 + j0) = r;
    }
  }
}

extern "C" void kernel_launch(void* const* d_in, const int* in_sizes, int n_in,
                              void* d_out, int out_size, void* d_ws, size_t ws_size,
                              hipStream_t stream) {
  (void)in_sizes; (void)n_in; (void)out_size; (void)ws_size;
  const float* query = (const float*)d_in[0];
  const float* key   = (const float*)d_in[1];
  const float* value = (const float*)d_in[2];
  const float* Wq = (const float*)d_in[3];
  const float* bq = (const float*)d_in[4];
  const float* Wk = (const float*)d_in[5];
  const float* bk = (const float*)d_in[6];
  const float* Wv = (const float*)d_in[7];
  const float* bv = (const float*)d_in[8];
  const float* Wo = (const float*)d_in[9];
  const float* bo = (const float*)d_in[10];
  float* out = (float*)d_out;

  u16* ws = (u16*)d_ws;
  u16* kfrag = ws;                // [256*8][8][64][8]
  u16* vt3   = kfrag + 8388608;   // [256*8][2][8][64][4]
  u16* qp    = vt3 + 8388608;     // [256][256] row-major
  u16* wof   = qp + 65536;        // [8][16][64][8] K=32 frags
  u16* wfq   = wof + 65536;
  u16* wfk   = wfq + 65536;
  u16* wfv   = wfk + 65536;

  wcvt_kernel<<<128, 256, 0, stream>>>(Wq, Wk, Wv, Wo, wfq, wfk, wfv, wof);
  proj_all_kernel<<<4112, 256, 0, stream>>>(query, key, value, wfq, wfk, wfv,
                                            bq, bk, bv, qp, kfrag, vt3);
  fused_attn_kernel<<<512, 512, 0, stream>>>(qp, kfrag, vt3, wof, bo, out);
}

// Round 24
// 69.770 us; speedup vs baseline: 1.0352x; 1.0352x over previous
//
#include <hip/hip_runtime.h>

// TempCtxAttention — R19-exact revert (best measured: 69.8us). qa-prefetch removed (R23: -2.4us).
// ws (u16): kfrag[8388608] | vt3[8388608] | qp[65536] | wof[65536] | wfq[65536] | wfk[65536] | wfv[65536]
// kfrag: QK A-frags [m][h][kt(8)][ln(64)][8]   ln=(d>>3)*16+(kl&15), elem d&7
// vt3 : PV A-frags  [m][h][jt(2)][kt(8)][ln(64)][4]  ln=((kl>>2)&3)*16+(d&15), elem kl&3, jt=d>>4
// qp  : row-major [n][256]
// wof : outproj K=32 A-frags [h(8)][jtile(16)][ln(64)][8]
// wf* : proj W frags [jtile(16)][kk(8)][ln(64)][8]

typedef unsigned short u16;
typedef unsigned int u32;
typedef __attribute__((ext_vector_type(8))) _Float16 half8;
typedef __attribute__((ext_vector_type(4))) _Float16 half4;
typedef __attribute__((ext_vector_type(4))) float f32x4;
typedef __attribute__((ext_vector_type(4))) unsigned short us4;
typedef __attribute__((ext_vector_type(2))) unsigned int u32x2;

__device__ __forceinline__ u16 f2h(float v) {
  _Float16 h = (_Float16)v;
  return __builtin_bit_cast(u16, h);
}
__device__ __forceinline__ u32 pk2(float lo, float hi) {
  return (u32)f2h(lo) | ((u32)f2h(hi) << 16);
}
__device__ __forceinline__ u32 pkrtz(float lo, float hi) {   // v_cvt_pkrtz_f16_f32
  return __builtin_bit_cast(u32, __builtin_amdgcn_cvt_pkrtz(lo, hi));
}
__device__ __forceinline__ f32x4 mf16(half8 a, half8 b, f32x4 c) {
  return __builtin_amdgcn_mfma_f32_16x16x32_f16(a, b, c, 0, 0, 0);
}
__device__ __forceinline__ f32x4 mf16k16(half4 a, half4 b, f32x4 c) {
  return __builtin_amdgcn_mfma_f32_16x16x16f16(a, b, c, 0, 0, 0);
}
__device__ __forceinline__ void gload_lds16(const void* g, void* l) {
  __builtin_amdgcn_global_load_lds((const __attribute__((address_space(1))) u32*)g,
                                   (__attribute__((address_space(3))) u32*)l, 16, 0, 0);
}

// ---------------- weight conversion: f32 -> f16 pre-fragmented ----------------
__global__ __launch_bounds__(256) void wcvt_kernel(const float* __restrict__ Wq,
                                                   const float* __restrict__ Wk,
                                                   const float* __restrict__ Wv,
                                                   const float* __restrict__ Wo,
                                                   u16* __restrict__ wfq, u16* __restrict__ wfk,
                                                   u16* __restrict__ wfv, u16* __restrict__ wof) {
  int t = blockIdx.x * 256 + threadIdx.x;     // [0, 32768)
  int widx = t >> 13, tl = t & 8191;          // 8192 entries per matrix
  int ln = tl & 63, kk = (tl >> 6) & 7, jt = tl >> 9;   // jt in [0,16)
  const float* src = widx == 0 ? Wq : widx == 1 ? Wk : widx == 2 ? Wv : Wo;
  u16* dst = widx == 0 ? wfq : widx == 1 ? wfk : widx == 2 ? wfv : wof;
  int j = jt * 16 + (ln & 15);
  int k0 = kk * 32 + (ln >> 4) * 8;
  float4 g0 = *(const float4*)(src + j * 256 + k0);
  float4 g1 = *(const float4*)(src + j * 256 + k0 + 4);
  us4 h0 = { f2h(g0.x), f2h(g0.y), f2h(g0.z), f2h(g0.w) };
  us4 h1 = { f2h(g1.x), f2h(g1.y), f2h(g1.z), f2h(g1.w) };
  int idx8 = (widx == 3) ? ((kk * 16 + jt) * 64 + ln)     // wof: head(kk)-major, K=32 frags
                         : ((jt * 8 + kk) * 64 + ln);     // wf : jtile-major
  *(us4*)(dst + idx8 * 8) = h0;
  *(us4*)(dst + idx8 * 8 + 4) = h1;
}

// ---------------- merged projections (R19-measured structure) ----------------
// grid 4112: [0,2048) K (mode1) ; [2048,4096) V (mode2) ; [4096,4112) Q (mode0)
__global__ __launch_bounds__(256, 4) void proj_all_kernel(const float* __restrict__ query,
                                                          const float* __restrict__ key,
                                                          const float* __restrict__ value,
                                                          const u16* __restrict__ wfq,
                                                          const u16* __restrict__ wfk,
                                                          const u16* __restrict__ wfv,
                                                          const float* __restrict__ bq,
                                                          const float* __restrict__ bk,
                                                          const float* __restrict__ bv,
                                                          u16* __restrict__ qp,
                                                          u16* __restrict__ kfrag,
                                                          u16* __restrict__ vt3) {
  __shared__ __align__(16) u16 xa[64 * 256];    // 32 KB f16, XOR-swizzled
  int bid = blockIdx.x;
  int mode, logical;
  const float* X; const u16* wf; const float* bias; u16* out;
  if (bid < 2048) {
    mode = 1; X = key; wf = wfk; bias = bk; out = kfrag;
    logical = (bid & 7) * 256 + (bid >> 3);
  } else if (bid < 4096) {
    int b = bid - 2048;
    mode = 2; X = value; wf = wfv; bias = bv; out = vt3;
    logical = (b & 7) * 256 + (b >> 3);
  } else {
    mode = 0; X = query; wf = wfq; bias = bq; out = qp;
    logical = bid - 4096;
  }
  int rb = logical >> 2, cb = logical & 3;
  int tid = threadIdx.x;
  char* xb = (char*)xa;
#pragma unroll
  for (int i = 0; i < 16; ++i) {
    int idx = tid + i * 256;
    int row = idx >> 6, c4 = idx & 63;
    int so = (row * 512 + c4 * 8) ^ ((row & 7) << 4);
    float4 gx = *(const float4*)(X + (rb * 64 + row) * 256 + c4 * 4);
    us4 hx = { f2h(gx.x), f2h(gx.y), f2h(gx.z), f2h(gx.w) };
    *(us4*)(xb + so) = hx;
  }
  __syncthreads();

  int lane = tid & 63, w = tid >> 6;
  int lr = lane & 15, lq = lane >> 4;

  if (mode == 2) {
    // direct: A = X rows (this wave: w*16..+16), B = W cols; D[row=kl][col=j]
    half8 a[8];
#pragma unroll
    for (int kk = 0; kk < 8; ++kk)
      a[kk] = *(const half8*)(xb + (((w * 16 + lr) * 512 + kk * 64 + lq * 16) ^ ((lr & 7) << 4)));
#pragma unroll
    for (int ct = 0; ct < 4; ++ct) {
      int jtile = cb * 4 + ct;
      f32x4 acc = {0.f, 0.f, 0.f, 0.f};
#pragma unroll
      for (int kk = 0; kk < 8; ++kk) {
        half8 b = *(const half8*)(wf + ((jtile * 8 + kk) * 64 + lane) * 8);
        acc = mf16(a[kk], b, acc);
      }
      int j = jtile * 16 + lr;
      float bj = bias[j];
      int h = j >> 5, d = j & 31;
      int gr0 = rb * 64 + w * 16 + lq * 4;     // 4 consecutive kl (elem = kl&3)
      int mm = gr0 >> 7, kl0 = gr0 & 127;
      int base = (((mm * 8 + h) * 2 + (d >> 4)) * 8 + (kl0 >> 4)) * 256
               + (((kl0 >> 2) & 3) * 16 + (d & 15)) * 4;
      us4 st = { f2h(acc[0] + bj), f2h(acc[1] + bj), f2h(acc[2] + bj), f2h(acc[3] + bj) };
      *(us4*)(out + base) = st;
    }
  } else {
    // transposed: A = W (wave jtile = cb*4+w), B = X; D[row=j][col=gr]
    int jtile = cb * 4 + w;
    half8 a[8];
#pragma unroll
    for (int kk = 0; kk < 8; ++kk)
      a[kk] = *(const half8*)(wf + ((jtile * 8 + kk) * 64 + lane) * 8);
    int j0 = jtile * 16 + lq * 4;              // 4 consecutive j (= d)
    float4 bv4 = *(const float4*)(bias + j0);
    int h = j0 >> 5, d0 = j0 & 31;
#pragma unroll
    for (int ct = 0; ct < 4; ++ct) {
      f32x4 acc = {0.f, 0.f, 0.f, 0.f};
#pragma unroll
      for (int kk = 0; kk < 8; ++kk) {
        half8 b = *(const half8*)(xb + (((ct * 16 + lr) * 512 + kk * 64 + lq * 16) ^ ((lr & 7) << 4)));
        acc = mf16(a[kk], b, acc);
      }
      int gr = rb * 64 + ct * 16 + lr;
      us4 st = { f2h(acc[0] + bv4.x), f2h(acc[1] + bv4.y), f2h(acc[2] + bv4.z), f2h(acc[3] + bv4.w) };
      if (mode == 0) {
        *(us4*)(out + gr * 256 + j0) = st;     // qp row-major [n][256]
      } else {
        int mm = gr >> 7, kl = gr & 127;
        int idx = (mm * 8 + h) * 4096 + (kl >> 4) * 512
                + ((d0 >> 3) * 16 + (kl & 15)) * 8 + (d0 & 7);
        *(us4*)(out + idx) = st;
      }
    }
  }
}

// ---------------- fused attention + output projection (R19-exact) --------------------------
__global__ __launch_bounds__(512, 4) void fused_attn_kernel(const u16* __restrict__ qp,
                                                            const u16* __restrict__ kp,
                                                            const u16* __restrict__ vt3,
                                                            const u16* __restrict__ wof,
                                                            const float* __restrict__ bo,
                                                            float* __restrict__ out) {
  __shared__ __align__(16) u16 kbuf[2][4096];   // per-head QK A-frags, dbuf
  __shared__ __align__(16) u16 vbuf[2][4096];   // per-head PV A-frags, dbuf
  __shared__ __align__(16) u16 cbuf[2][4096];   // per-head ctx B-frags [nb][lane][8], dbuf

  const int bid = blockIdx.x;
  const int xcd = bid & 7, idx = bid >> 3;
  const int m = xcd * 32 + (idx >> 1);
  const int nh = idx & 1;
  const int tid = threadIdx.x;
  const int w = tid >> 6, lane = tid & 63;
  const int lr = lane & 15, lq = lane >> 4;
  const int n0 = nh * 128 + w * 16;
  const float SCL2E = 0.25506980508f;           // log2(e)/sqrt(32)

  const char* kg = (const char*)(kp + m * 8 * 4096);   // 8KB per head
  const char* vg = (const char*)(vt3 + m * 8 * 4096);

  gload_lds16(kg + w * 1024 + lane * 16, (char*)(&kbuf[0][0]) + w * 1024);
  gload_lds16(vg + w * 1024 + lane * 16, (char*)(&vbuf[0][0]) + w * 1024);
  __syncthreads();

  f32x4 accO[2][8];
#pragma unroll
  for (int jt = 0; jt < 2; ++jt)
#pragma unroll
    for (int nb = 0; nb < 8; ++nb) accO[jt][nb] = f32x4{0.f, 0.f, 0.f, 0.f};

  for (int h = 0; h < 8; ++h) {
    const int cur = h & 1;
    char* kb = (char*)(&kbuf[cur][0]);
    char* vb = (char*)(&vbuf[cur][0]);
    char* cb = (char*)(&cbuf[cur][0]);
    if (h < 7) {   // stage next head; drained by this head's __syncthreads
      gload_lds16(kg + (h + 1) * 8192 + w * 1024 + lane * 16, (char*)(&kbuf[cur ^ 1][0]) + w * 1024);
      gload_lds16(vg + (h + 1) * 8192 + w * 1024 + lane * 16, (char*)(&vbuf[cur ^ 1][0]) + w * 1024);
    }
    half8 qa = *(const half8*)(qp + (n0 + lr) * 256 + h * 32 + lq * 8);
    // ---- scores^T ----
    f32x4 s[8];
    __builtin_amdgcn_s_setprio(1);
#pragma unroll
    for (int kt = 0; kt < 8; ++kt) {
      half8 ka = *(const half8*)(kb + kt * 1024 + lane * 16);
      f32x4 z = {0.f, 0.f, 0.f, 0.f};
      s[kt] = mf16(ka, qa, z);
    }
    __builtin_amdgcn_s_setprio(0);
    // ---- max-free softmax: exp2 direct, pkrtz pack, 2 shfl for sum ----
    float sA = 0.f, sB = 0.f;
    half4 pb[8];
#pragma unroll
    for (int kt = 0; kt < 8; ++kt) {
      float p0 = __builtin_amdgcn_exp2f(s[kt][0] * SCL2E);
      float p1 = __builtin_amdgcn_exp2f(s[kt][1] * SCL2E);
      float p2 = __builtin_amdgcn_exp2f(s[kt][2] * SCL2E);
      float p3 = __builtin_amdgcn_exp2f(s[kt][3] * SCL2E);
      sA += p0 + p1; sB += p2 + p3;
      u32x2 pw = { pkrtz(p0, p1), pkrtz(p2, p3) };
      pb[kt] = __builtin_bit_cast(half4, pw);
    }
    float sum = sA + sB;
    sum += __shfl_xor(sum, 16);
    sum += __shfl_xor(sum, 32);
    float inv = 1.0f / sum;
    // ---- PV ----
    f32x4 a0 = {0.f, 0.f, 0.f, 0.f}, a1 = {0.f, 0.f, 0.f, 0.f};
    __builtin_amdgcn_s_setprio(1);
#pragma unroll
    for (int kt = 0; kt < 8; ++kt) {
      half4 v0 = *(const half4*)(vb + kt * 512 + lane * 8);
      a0 = mf16k16(v0, pb[kt], a0);
      half4 v1 = *(const half4*)(vb + 4096 + kt * 512 + lane * 8);
      a1 = mf16k16(v1, pb[kt], a1);
    }
    __builtin_amdgcn_s_setprio(0);
    // ---- wof loads issued here (hoisted): complete during the barrier's vmcnt drain ----
    half8 wv0 = *(const half8*)(wof + ((h * 16 + w * 2 + 0) * 64 + lane) * 8);
    half8 wv1 = *(const half8*)(wof + ((h * 16 + w * 2 + 1) * 64 + lane) * 8);
    // ---- ctx frags -> LDS (outproj K=32 B-frag layout) ----
    u32x2 c0 = { pk2(a0[0] * inv, a0[1] * inv), pk2(a0[2] * inv, a0[3] * inv) };
    u32x2 c1 = { pk2(a1[0] * inv, a1[1] * inv), pk2(a1[2] * inv, a1[3] * inv) };
    const int cwo = w * 1024 + ((lq >> 1) * 16 + lr) * 16 + (lq & 1) * 8;
    *(u32x2*)(cb + cwo) = c0;
    *(u32x2*)(cb + cwo + 512) = c1;
    __syncthreads();
    // ---- out-proj ----
    __builtin_amdgcn_s_setprio(1);
#pragma unroll
    for (int nb = 0; nb < 8; ++nb) {
      half8 cf = *(const half8*)(cb + nb * 1024 + lane * 16);
      accO[0][nb] = mf16(wv0, cf, accO[0][nb]);
      accO[1][nb] = mf16(wv1, cf, accO[1][nb]);
    }
    __builtin_amdgcn_s_setprio(0);
  }
#pragma unroll
  for (int jt = 0; jt < 2; ++jt) {
    const int j0 = w * 32 + jt * 16 + lq * 4;
    float4 bv = *(const float4*)(bo + j0);
#pragma unroll
    for (int nb = 0; nb < 8; ++nb) {
      const int n = nh * 128 + nb * 16 + lr;
      float4 r;
      r.x = accO[jt][nb][0] + bv.x;
      r.y = accO[jt][nb][1] + bv.y;
      r.z = accO[jt][nb][2] + bv.z;
      r.w = accO[jt][nb][3] + bv.w;
      *(float4*)(out + (n * 256 + m) * 256 + j0) = r;
    }
  }
}

extern "C" void kernel_launch(void* const* d_in, const int* in_sizes, int n_in,
                              void* d_out, int out_size, void* d_ws, size_t ws_size,
                              hipStream_t stream) {
  (void)in_sizes; (void)n_in; (void)out_size; (void)ws_size;
  const float* query = (const float*)d_in[0];
  const float* key   = (const float*)d_in[1];
  const float* value = (const float*)d_in[2];
  const float* Wq = (const float*)d_in[3];
  const float* bq = (const float*)d_in[4];
  const float* Wk = (const float*)d_in[5];
  const float* bk = (const float*)d_in[6];
  const float* Wv = (const float*)d_in[7];
  const float* bv = (const float*)d_in[8];
  const float* Wo = (const float*)d_in[9];
  const float* bo = (const float*)d_in[10];
  float* out = (float*)d_out;

  u16* ws = (u16*)d_ws;
  u16* kfrag = ws;                // [256*8][8][64][8]
  u16* vt3   = kfrag + 8388608;   // [256*8][2][8][64][4]
  u16* qp    = vt3 + 8388608;     // [256][256] row-major
  u16* wof   = qp + 65536;        // [8][16][64][8] K=32 frags
  u16* wfq   = wof + 65536;
  u16* wfk   = wfq + 65536;
  u16* wfv   = wfk + 65536;

  wcvt_kernel<<<128, 256, 0, stream>>>(Wq, Wk, Wv, Wo, wfq, wfk, wfv, wof);
  proj_all_kernel<<<4112, 256, 0, stream>>>(query, key, value, wfq, wfk, wfv,
                                            bq, bk, bv, qp, kfrag, vt3);
  fused_attn_kernel<<<512, 512, 0, stream>>>(qp, kfrag, vt3, wof, bo, out);
}